// Round 13
// baseline (639.035 us; speedup 1.0000x reference)
//
#include <hip/hip_runtime.h>
#include <hip/hip_bf16.h>
#include <stdint.h>

typedef unsigned short ushortT;
typedef __bf16 bf16x8 __attribute__((ext_vector_type(8)));
typedef float f32x4 __attribute__((ext_vector_type(4)));

#define N_TOK 131072
#define NSEG  256
#define RSPL  8

__device__ __forceinline__ uint32_t f2bf(float f) {
  union { float f; uint32_t u; } c; c.f = f;
  uint32_t u = c.u;
  u += 0x7fffu + ((u >> 16) & 1u);   // RNE
  return u >> 16;
}
__device__ __forceinline__ float bf2f(uint32_t b) {
  union { uint32_t u; float f; } c; c.u = b << 16;
  return c.f;
}

__device__ __forceinline__ void gload_lds16(const void* g, void* l) {
  __builtin_amdgcn_global_load_lds(
      (const __attribute__((address_space(1))) void*)g,
      (__attribute__((address_space(3))) void*)l, 16, 0, 0);
}

// ---------------- prep kernels ----------------

// WT[n*Kd + k] = bf16(W[k*Nd + n]);  W is [Kd][Nd] row-major
__global__ void transpose_bf16_kernel(const float* __restrict__ W, ushortT* __restrict__ WT,
                                      int Kd, int Nd) {
  int i = blockIdx.x * 256 + threadIdx.x;
  if (i < Kd * Nd) {
    int n = i / Kd, k = i % Kd;
    WT[i] = (ushortT)f2bf(W[(size_t)k * Nd + n]);
  }
}

// weffT[h][c] = bf16( sum_d Wk[c,h*128+d]*Wq[h,d] / sqrt(128) ), h<8; rows 8..15 zero
__global__ void weff_kernel(const float* __restrict__ Wk, const float* __restrict__ Wq,
                            ushortT* __restrict__ weffT) {
  const int c = blockIdx.x;       // 640
  const int lane = threadIdx.x;   // 64
  const float rs = 0.08838834764831845f;
#pragma unroll
  for (int h = 0; h < 8; ++h) {
    float acc = Wk[(size_t)c * 1024 + h * 128 + lane] * Wq[h * 128 + lane]
              + Wk[(size_t)c * 1024 + h * 128 + 64 + lane] * Wq[h * 128 + 64 + lane];
#pragma unroll
    for (int off = 32; off >= 1; off >>= 1) acc += __shfl_xor(acc, off, 64);
    if (lane == 0) {
      weffT[h * 640 + c]       = (ushortT)f2bf(acc * rs);
      weffT[(h + 8) * 640 + c] = 0;
    }
  }
}

// gbnd[s] = first index with seg[i] >= s, s in [0, 256]
__global__ void seg_bounds_kernel(const int* __restrict__ seg, int* __restrict__ gbnd) {
  const int s = (int)threadIdx.x + (int)blockIdx.x * 512;
  if (s > NSEG) return;
  int lo = 0, hi = N_TOK;
  while (lo < hi) { int m = (lo + hi) >> 1; if (seg[m] < s) lo = m + 1; else hi = m; }
  gbnd[s] = lo;
}

// ---------------- m97-style GEMM: C[M,512] = relu?(A[M,K] @ W + bias) ----------------
// R12 structure (validated: conflicts=0, 780 TF). OUTP (XF32 layer only):
// waves additionally compute the X@weff[0:128] partial for this block's 128
// rows (wave w owns rows w*32..w*32+31) and write f32 to outp — final_mfma
// then skips re-reading X (67 MB f32/chunk saved). Only bn==0 blocks write.

template <int K, bool RELU, bool BIAS, bool XF32, bool OUTP>
__global__ __launch_bounds__(256, 4)
void gemm_m97_kernel(const void* __restrict__ Av, const ushortT* __restrict__ BT,
                     const float* __restrict__ bias, ushortT* __restrict__ C,
                     const ushortT* __restrict__ weffT, float* __restrict__ outp) {
  __shared__ ushortT lA[128 * 64];
  __shared__ ushortT lB[128 * 64];
  constexpr int NT = K / 64;

  const int nwg  = (int)gridDim.x;
  const int cpx  = nwg >> 3;
  const int flat = (int)blockIdx.x;
  const int swz  = (flat & 7) * cpx + (flat >> 3);
  const int bm   = swz >> 2;
  const int bn   = swz & 3;

  const int t = (int)threadIdx.x;
  const int w = t >> 6, lane = t & 63;
  const int wm = w >> 1, wn = w & 1;
  const int q = lane >> 4, lr = lane & 15;

  const int srow = t >> 3;
  const int slc  = (t & 7) ^ (srow & 7);

  const ushortT* Ab = nullptr;
  const float*   Xf = nullptr;
  if (XF32) Xf = (const float*)Av + (size_t)(bm * 128 + srow) * 128 + slc * 8;
  else      Ab = (const ushortT*)Av + (size_t)(bm * 128 + srow) * K + slc * 8;
  const ushortT* Bg = BT + (size_t)(bn * 128 + srow) * K + slc * 8;

  f32x4 acc[4][4];
#pragma unroll
  for (int i = 0; i < 4; ++i)
#pragma unroll
    for (int j = 0; j < 4; ++j) acc[i][j] = 0.f;

  // X@Wx partial state (OUTP path): B-frags of weffT rows (head=lr), K=128
  f32x4 acc_out[2];
  bf16x8 wxf[2][2];
  if (OUTP) {
    acc_out[0] = 0.f; acc_out[1] = 0.f;
#pragma unroll
    for (int kt = 0; kt < 2; ++kt)
#pragma unroll
      for (int kk = 0; kk < 2; ++kk)
        wxf[kt][kk] = *(const bf16x8*)(weffT + lr * 640 + kt * 64 + kk * 32 + q * 8);
  }

  const int cc0 = (q ^ (lr & 7)) << 4;
  const int cc1 = ((4 + q) ^ (lr & 7)) << 4;
  const char* lAc = (const char*)lA;
  const char* lBc = (const char*)lB;

#pragma unroll 1
  for (int kt = 0; kt < NT; ++kt) {
    {
      const ushortT* src = Bg + kt * 64;
#pragma unroll
      for (int j = 0; j < 4; ++j)
        gload_lds16(src + (size_t)j * 32 * K, (char*)lB + j * 4096 + t * 16);
    }
    if (XF32) {
      const float* src = Xf + kt * 64;
#pragma unroll
      for (int j = 0; j < 4; ++j) {
        const float4 v0 = *(const float4*)(src + (size_t)j * 32 * 128);
        const float4 v1 = *(const float4*)(src + (size_t)j * 32 * 128 + 4);
        uint4 pk;
        pk.x = f2bf(v0.x) | (f2bf(v0.y) << 16);
        pk.y = f2bf(v0.z) | (f2bf(v0.w) << 16);
        pk.z = f2bf(v1.x) | (f2bf(v1.y) << 16);
        pk.w = f2bf(v1.z) | (f2bf(v1.w) << 16);
        *(uint4*)((char*)lA + j * 4096 + t * 16) = pk;
      }
    } else {
      const ushortT* src = Ab + kt * 64;
#pragma unroll
      for (int j = 0; j < 4; ++j)
        gload_lds16(src + (size_t)j * 32 * K, (char*)lA + j * 4096 + t * 16);
    }
    __syncthreads();

    bf16x8 a0[4], a1[4], b0[4], b1[4];
#pragma unroll
    for (int m = 0; m < 4; ++m) {
      const int ro = (wm * 64 + m * 16 + lr) * 128;
      a0[m] = *(const bf16x8*)(lAc + ro + cc0);
      a1[m] = *(const bf16x8*)(lAc + ro + cc1);
    }
#pragma unroll
    for (int n = 0; n < 4; ++n) {
      const int ro = (wn * 64 + n * 16 + lr) * 128;
      b0[n] = *(const bf16x8*)(lBc + ro + cc0);
      b1[n] = *(const bf16x8*)(lBc + ro + cc1);
    }

    __builtin_amdgcn_s_setprio(1);
#pragma unroll
    for (int n = 0; n < 4; ++n)
#pragma unroll
      for (int m = 0; m < 4; ++m)
        acc[m][n] = __builtin_amdgcn_mfma_f32_16x16x32_bf16(a0[m], b0[n], acc[m][n], 0, 0, 0);
#pragma unroll
    for (int n = 0; n < 4; ++n)
#pragma unroll
      for (int m = 0; m < 4; ++m)
        acc[m][n] = __builtin_amdgcn_mfma_f32_16x16x32_bf16(a1[m], b1[n], acc[m][n], 0, 0, 0);
    __builtin_amdgcn_s_setprio(0);

    if (OUTP && bn == 0) {
      // wave w covers block rows w*32..w*32+31 (2 m-frags)
#pragma unroll
      for (int mi = 0; mi < 2; ++mi) {
        const int ro = (w * 32 + mi * 16 + lr) * 128;
        const bf16x8 xa0 = *(const bf16x8*)(lAc + ro + cc0);
        const bf16x8 xa1 = *(const bf16x8*)(lAc + ro + cc1);
        acc_out[mi] = __builtin_amdgcn_mfma_f32_16x16x32_bf16(xa0, wxf[kt][0], acc_out[mi], 0, 0, 0);
        acc_out[mi] = __builtin_amdgcn_mfma_f32_16x16x32_bf16(xa1, wxf[kt][1], acc_out[mi], 0, 0, 0);
      }
    }
    __syncthreads();
  }

  if (OUTP && bn == 0 && lr < 8) {
#pragma unroll
    for (int mi = 0; mi < 2; ++mi)
#pragma unroll
      for (int r = 0; r < 4; ++r)
        outp[(size_t)(bm * 128 + w * 32 + mi * 16 + q * 4 + r) * 8 + lr] = acc_out[mi][r];
  }

  const int row0 = bm * 128 + wm * 64 + q * 4;
  const int col0 = bn * 128 + wn * 64 + lr;
#pragma unroll
  for (int n = 0; n < 4; ++n) {
    const int col = col0 + n * 16;
    const float bvv = BIAS ? bias[col] : 0.f;
#pragma unroll
    for (int m = 0; m < 4; ++m) {
#pragma unroll
      for (int r = 0; r < 4; ++r) {
        float v = acc[m][n][r] + bvv;
        if (RELU) v = fmaxf(v, 0.f);
        C[(size_t)(row0 + m * 16 + r) * 512 + col] = (ushortT)f2bf(v);
      }
    }
  }
}

// ---------------- two-pass segment prefix-mean (unchanged) ----------------

__global__ __launch_bounds__(256)
void seg_sum_kernel(const ushortT* __restrict__ z, const int* __restrict__ gbnd,
                    float* __restrict__ part, int c0, int rows) {
  const int s  = (int)blockIdx.x >> 3;
  const int rg = (int)blockIdx.x & 7;
  const int t  = (int)threadIdx.x;

  const int gb0 = gbnd[s], gb1 = gbnd[s + 1];
  int beg = gb0 > c0 ? gb0 : c0;
  int end = gb1 < c0 + rows ? gb1 : c0 + rows;
  int len = end - beg; if (len < 0) len = 0;
  const int r0 = beg + ((len * rg) >> 3);
  const int r1 = beg + ((len * (rg + 1)) >> 3);

  float a0 = 0.f, a1 = 0.f;
  const uint32_t* __restrict__ zp = (const uint32_t*)z;
  int r = r0;
  for (; r + 8 <= r1; r += 8) {
    uint32_t v[8];
#pragma unroll
    for (int i = 0; i < 8; ++i) v[i] = zp[(size_t)(r + i - c0) * 256 + t];
#pragma unroll
    for (int i = 0; i < 8; ++i) { a0 += bf2f(v[i] & 0xffffu); a1 += bf2f(v[i] >> 16); }
  }
  for (; r < r1; ++r) {
    const uint32_t v = zp[(size_t)(r - c0) * 256 + t];
    a0 += bf2f(v & 0xffffu); a1 += bf2f(v >> 16);
  }
  float2 pv; pv.x = a0; pv.y = a1;
  ((float2*)part)[(s * 8 + rg) * 256 + t] = pv;
}

__global__ __launch_bounds__(256)
void seg_scan2_kernel(const ushortT* __restrict__ z, ushortT* __restrict__ gout,
                      const int* __restrict__ gbnd, const float* __restrict__ br,
                      const float* __restrict__ part,
                      const float* __restrict__ cin, float* __restrict__ cout,
                      int c0, int rows) {
  const int s  = (int)blockIdx.x >> 3;
  const int rg = (int)blockIdx.x & 7;
  const int t  = (int)threadIdx.x;

  const int gb0 = gbnd[s], gb1 = gbnd[s + 1];
  int beg = gb0 > c0 ? gb0 : c0;
  int end = gb1 < c0 + rows ? gb1 : c0 + rows;
  int len = end - beg; if (len < 0) len = 0;
  const int r0 = beg + ((len * rg) >> 3);
  const int r1 = beg + ((len * (rg + 1)) >> 3);

  const float2 cv = ((const float2*)cin)[s * 256 + t];
  float a0 = cv.x, a1 = cv.y;
  for (int q2 = 0; q2 < rg; ++q2) {
    const float2 pv = ((const float2*)part)[(s * 8 + q2) * 256 + t];
    a0 += pv.x; a1 += pv.y;
  }
  int cb = c0 - gb0; if (cb < 0) cb = 0;
  const int seglen = gb1 - gb0; if (cb > seglen) cb = seglen;
  const int cnt0 = cb + (r0 - beg);

  const float b0 = br[2 * t], b1v = br[2 * t + 1];
  const uint32_t* __restrict__ zp = (const uint32_t*)z;
  uint32_t* __restrict__ gp = (uint32_t*)gout;

  int r = r0;
  for (; r + 8 <= r1; r += 8) {
    uint32_t v[8];
#pragma unroll
    for (int i = 0; i < 8; ++i) v[i] = zp[(size_t)(r + i - c0) * 256 + t];
#pragma unroll
    for (int i = 0; i < 8; ++i) {
      a0 += bf2f(v[i] & 0xffffu);
      a1 += bf2f(v[i] >> 16);
      const float inv = 1.0f / (float)(cnt0 + (r + i) - r0 + 1);
      const float g0 = fmaxf(fmaf(a0, inv, b0), 0.f);
      const float g1 = fmaxf(fmaf(a1, inv, b1v), 0.f);
      gp[(size_t)(r + i - c0) * 256 + t] = f2bf(g0) | (f2bf(g1) << 16);
    }
  }
  for (; r < r1; ++r) {
    const uint32_t v = zp[(size_t)(r - c0) * 256 + t];
    a0 += bf2f(v & 0xffffu);
    a1 += bf2f(v >> 16);
    const float inv = 1.0f / (float)(cnt0 + r - r0 + 1);
    const float g0 = fmaxf(fmaf(a0, inv, b0), 0.f);
    const float g1 = fmaxf(fmaf(a1, inv, b1v), 0.f);
    gp[(size_t)(r - c0) * 256 + t] = f2bf(g0) | (f2bf(g1) << 16);
  }

  if (rg == 7) {
    float2 co; co.x = a0; co.y = a1;
    ((float2*)cout)[s * 256 + t] = co;
  }
}

// ---------------- final via MFMA: out[n,h] = partial(X@Wx) + g[n,:]@Wg ----------------
// acc init from the f32 partial written by gemm1 (same D-layout mapping),
// then 16 g-only MFMA steps. No X re-read.

__global__ __launch_bounds__(256)
void final_mfma_kernel(const ushortT* __restrict__ g,
                       const ushortT* __restrict__ weffT, float* __restrict__ out) {
  __shared__ char lw[16 * 1296];
  const int t = (int)threadIdx.x;

#pragma unroll
  for (int i = 0; i < 5; ++i) {
    const int idx = i * 256 + t;
    const int row = idx / 80, c = idx % 80;
    *(uint4*)(lw + row * 1296 + c * 16) =
        *(const uint4*)((const char*)weffT + row * 1280 + c * 16);
  }
  __syncthreads();

  const int wv = t >> 6, lane = t & 63;
  const int q = lane >> 4, lr = lane & 15;
  const int rbase = (int)blockIdx.x * 128 + wv * 32;

  f32x4 acc[2];
  acc[0] = 0.f; acc[1] = 0.f;
  if (lr < 8) {
#pragma unroll
    for (int mt = 0; mt < 2; ++mt)
#pragma unroll
      for (int r = 0; r < 4; ++r)
        acc[mt][r] = out[(size_t)(rbase + mt * 16 + q * 4 + r) * 8 + lr];
  }

#pragma unroll
  for (int kk = 0; kk < 16; ++kk) {
    const bf16x8 b = *(const bf16x8*)(lw + lr * 1296 + (kk + 4) * 64 + q * 16);
#pragma unroll
    for (int mt = 0; mt < 2; ++mt) {
      const int row = rbase + mt * 16 + lr;
      const bf16x8 a = *(const bf16x8*)(g + (size_t)row * 512 + kk * 32 + q * 8);
      acc[mt] = __builtin_amdgcn_mfma_f32_16x16x32_bf16(a, b, acc[mt], 0, 0, 0);
    }
  }

  if (lr < 8) {
#pragma unroll
    for (int mt = 0; mt < 2; ++mt)
#pragma unroll
      for (int r = 0; r < 4; ++r)
        out[(size_t)(rbase + mt * 16 + q * 4 + r) * 8 + lr] = acc[mt][r];
  }
}

// ---------------- launch ----------------

extern "C" void kernel_launch(void* const* d_in, const int* in_sizes, int n_in,
                              void* d_out, int out_size, void* d_ws, size_t ws_size,
                              hipStream_t stream) {
  const float* X  = (const float*)d_in[0];
  const int*   sg = (const int*)d_in[1];
  const float* W1 = (const float*)d_in[2];
  const float* b1 = (const float*)d_in[3];
  const float* W2 = (const float*)d_in[4];
  const float* b2 = (const float*)d_in[5];
  const float* W3 = (const float*)d_in[6];
  const float* b3 = (const float*)d_in[7];
  const float* Wr = (const float*)d_in[8];
  const float* br = (const float*)d_in[9];
  const float* Wk = (const float*)d_in[10];
  const float* Wq = (const float*)d_in[11];
  float* out = (float*)d_out;

  const size_t szW1T  = 512 * 128 * 2;
  const size_t szWT   = 512 * 512 * 2;
  const size_t szWeff = 16 * 640 * 2;
  const size_t szPart = (size_t)NSEG * RSPL * 256 * 2 * 4;
  const size_t szCar  = (size_t)NSEG * 256 * 2 * 4;
  const size_t szBnd  = (NSEG + 1) * 4;
  const size_t fixed  = szW1T + 3 * szWT + szWeff + szPart + 2 * szCar + szBnd + 512;

  int CH = 0;
  const int cands[6] = {131072, 65536, 32768, 16384, 8192, 4096};
  for (int i = 0; i < 6; ++i) {
    const size_t need = fixed + 2 * (size_t)cands[i] * 512 * 2;
    if (need <= ws_size) { CH = cands[i]; break; }
  }
  if (CH == 0) CH = 4096;

  char* p = (char*)d_ws;
  ushortT* W1T   = (ushortT*)p; p += szW1T;
  ushortT* W2T   = (ushortT*)p; p += szWT;
  ushortT* W3T   = (ushortT*)p; p += szWT;
  ushortT* WrT   = (ushortT*)p; p += szWT;
  ushortT* weffT = (ushortT*)p; p += szWeff;
  float*   part  = (float*)p;   p += szPart;
  float*   carA  = (float*)p;   p += szCar;
  float*   carB  = (float*)p;   p += szCar;
  int*     gbnd  = (int*)p;     p += (szBnd + 255) & ~255ull;
  ushortT* p1    = (ushortT*)p; p += (size_t)CH * 512 * 2;
  ushortT* p2    = (ushortT*)p;

  transpose_bf16_kernel<<<(512 * 128 + 255) / 256, 256, 0, stream>>>(W1, W1T, 128, 512);
  transpose_bf16_kernel<<<(512 * 512 + 255) / 256, 256, 0, stream>>>(W2, W2T, 512, 512);
  transpose_bf16_kernel<<<(512 * 512 + 255) / 256, 256, 0, stream>>>(W3, W3T, 512, 512);
  transpose_bf16_kernel<<<(512 * 512 + 255) / 256, 256, 0, stream>>>(Wr, WrT, 512, 512);
  weff_kernel<<<640, 64, 0, stream>>>(Wk, Wq, weffT);
  seg_bounds_kernel<<<1, 512, 0, stream>>>(sg, gbnd);
  hipMemsetAsync(carA, 0, szCar, stream);

  int par = 0;
  for (int c0 = 0; c0 < N_TOK; c0 += CH) {
    const int gG = (CH / 128) * 4;
    float* cin  = par ? carB : carA;
    float* cout = par ? carA : carB;
    float* outc = out + (size_t)c0 * 8;
    gemm_m97_kernel<128, true,  true,  true,  true ><<<gG, 256, 0, stream>>>(
        X + (size_t)c0 * 128, W1T, b1, p1, weffT, outc);
    gemm_m97_kernel<512, true,  true,  false, false><<<gG, 256, 0, stream>>>(
        p1, W2T, b2, p2, nullptr, nullptr);
    gemm_m97_kernel<512, true,  true,  false, false><<<gG, 256, 0, stream>>>(
        p2, W3T, b3, p1, nullptr, nullptr);
    gemm_m97_kernel<512, false, false, false, false><<<gG, 256, 0, stream>>>(
        p1, WrT, nullptr, p2, nullptr, nullptr);
    seg_sum_kernel <<<NSEG * RSPL, 256, 0, stream>>>(p2, gbnd, part, c0, CH);
    seg_scan2_kernel<<<NSEG * RSPL, 256, 0, stream>>>(p2, p1, gbnd, br, part,
                                                      cin, cout, c0, CH);
    final_mfma_kernel<<<CH / 128, 256, 0, stream>>>(p1, weffT, outc);
    par ^= 1;
  }
}

// Round 14
// 443.501 us; speedup vs baseline: 1.4409x; 1.4409x over previous
//
#include <hip/hip_runtime.h>
#include <hip/hip_bf16.h>
#include <stdint.h>

typedef unsigned short ushortT;
typedef __bf16 bf16x8 __attribute__((ext_vector_type(8)));
typedef float f32x4 __attribute__((ext_vector_type(4)));

#define N_TOK 131072
#define NSEG  256
#define RSPL  8

__device__ __forceinline__ uint32_t f2bf(float f) {
  union { float f; uint32_t u; } c; c.f = f;
  uint32_t u = c.u;
  u += 0x7fffu + ((u >> 16) & 1u);   // RNE
  return u >> 16;
}
__device__ __forceinline__ float bf2f(uint32_t b) {
  union { uint32_t u; float f; } c; c.u = b << 16;
  return c.f;
}

__device__ __forceinline__ void gload_lds16(const void* g, void* l) {
  __builtin_amdgcn_global_load_lds(
      (const __attribute__((address_space(1))) void*)g,
      (__attribute__((address_space(3))) void*)l, 16, 0, 0);
}

// ---------------- prep kernels ----------------

// WT[n*Kd + k] = bf16(W[k*Nd + n]);  W is [Kd][Nd] row-major
__global__ void transpose_bf16_kernel(const float* __restrict__ W, ushortT* __restrict__ WT,
                                      int Kd, int Nd) {
  int i = blockIdx.x * 256 + threadIdx.x;
  if (i < Kd * Nd) {
    int n = i / Kd, k = i % Kd;
    WT[i] = (ushortT)f2bf(W[(size_t)k * Nd + n]);
  }
}

// weffT[h][c] = bf16( sum_d Wk[c,h*128+d]*Wq[h,d] / sqrt(128) ), h<8; rows 8..15 zero
__global__ void weff_kernel(const float* __restrict__ Wk, const float* __restrict__ Wq,
                            ushortT* __restrict__ weffT) {
  const int c = blockIdx.x;       // 640
  const int lane = threadIdx.x;   // 64
  const float rs = 0.08838834764831845f;
#pragma unroll
  for (int h = 0; h < 8; ++h) {
    float acc = Wk[(size_t)c * 1024 + h * 128 + lane] * Wq[h * 128 + lane]
              + Wk[(size_t)c * 1024 + h * 128 + 64 + lane] * Wq[h * 128 + 64 + lane];
#pragma unroll
    for (int off = 32; off >= 1; off >>= 1) acc += __shfl_xor(acc, off, 64);
    if (lane == 0) {
      weffT[h * 640 + c]       = (ushortT)f2bf(acc * rs);
      weffT[(h + 8) * 640 + c] = 0;
    }
  }
}

// gbnd[s] = first index with seg[i] >= s, s in [0, 256]
__global__ void seg_bounds_kernel(const int* __restrict__ seg, int* __restrict__ gbnd) {
  const int s = (int)threadIdx.x + (int)blockIdx.x * 512;
  if (s > NSEG) return;
  int lo = 0, hi = N_TOK;
  while (lo < hi) { int m = (lo + hi) >> 1; if (seg[m] < s) lo = m + 1; else hi = m; }
  gbnd[s] = lo;
}

// ---------------- m97-style GEMM: C[M,512] = relu?(A[M,K] @ W + bias) ----------------
// R12 structure (validated: conflicts=0, 780 TF, VGPR 76 @ (256,3)).
// Launch bounds per instantiation: OUTP gemm1 needs +24 regs (wxf + acc_out)
// -> (256,2) budget 256, no spill; plain K=512 path -> (256,3), R12-measured.
// R13 lesson: (256,4) = budget 128 -> acc spills to scratch (192 MB WRITE,
// MfmaUtil 3.7%). Never below 3 waves/EU for this kernel.

template <int K, bool RELU, bool BIAS, bool XF32, bool OUTP>
__global__ __launch_bounds__(256, OUTP ? 2 : 3)
void gemm_m97_kernel(const void* __restrict__ Av, const ushortT* __restrict__ BT,
                     const float* __restrict__ bias, ushortT* __restrict__ C,
                     const ushortT* __restrict__ weffT, float* __restrict__ outp) {
  __shared__ ushortT lA[128 * 64];
  __shared__ ushortT lB[128 * 64];
  constexpr int NT = K / 64;

  const int nwg  = (int)gridDim.x;
  const int cpx  = nwg >> 3;
  const int flat = (int)blockIdx.x;
  const int swz  = (flat & 7) * cpx + (flat >> 3);
  const int bm   = swz >> 2;
  const int bn   = swz & 3;

  const int t = (int)threadIdx.x;
  const int w = t >> 6, lane = t & 63;
  const int wm = w >> 1, wn = w & 1;
  const int q = lane >> 4, lr = lane & 15;

  const int srow = t >> 3;
  const int slc  = (t & 7) ^ (srow & 7);

  const ushortT* Ab = nullptr;
  const float*   Xf = nullptr;
  if (XF32) Xf = (const float*)Av + (size_t)(bm * 128 + srow) * 128 + slc * 8;
  else      Ab = (const ushortT*)Av + (size_t)(bm * 128 + srow) * K + slc * 8;
  const ushortT* Bg = BT + (size_t)(bn * 128 + srow) * K + slc * 8;

  f32x4 acc[4][4];
#pragma unroll
  for (int i = 0; i < 4; ++i)
#pragma unroll
    for (int j = 0; j < 4; ++j) acc[i][j] = 0.f;

  // X@Wx partial state (OUTP path): B-frags of weffT rows (head=lr), K=128
  f32x4 acc_out[2];
  bf16x8 wxf[2][2];
  if (OUTP) {
    acc_out[0] = 0.f; acc_out[1] = 0.f;
#pragma unroll
    for (int kt = 0; kt < 2; ++kt)
#pragma unroll
      for (int kk = 0; kk < 2; ++kk)
        wxf[kt][kk] = *(const bf16x8*)(weffT + lr * 640 + kt * 64 + kk * 32 + q * 8);
  }

  const int cc0 = (q ^ (lr & 7)) << 4;
  const int cc1 = ((4 + q) ^ (lr & 7)) << 4;
  const char* lAc = (const char*)lA;
  const char* lBc = (const char*)lB;

#pragma unroll 1
  for (int kt = 0; kt < NT; ++kt) {
    {
      const ushortT* src = Bg + kt * 64;
#pragma unroll
      for (int j = 0; j < 4; ++j)
        gload_lds16(src + (size_t)j * 32 * K, (char*)lB + j * 4096 + t * 16);
    }
    if (XF32) {
      const float* src = Xf + kt * 64;
#pragma unroll
      for (int j = 0; j < 4; ++j) {
        const float4 v0 = *(const float4*)(src + (size_t)j * 32 * 128);
        const float4 v1 = *(const float4*)(src + (size_t)j * 32 * 128 + 4);
        uint4 pk;
        pk.x = f2bf(v0.x) | (f2bf(v0.y) << 16);
        pk.y = f2bf(v0.z) | (f2bf(v0.w) << 16);
        pk.z = f2bf(v1.x) | (f2bf(v1.y) << 16);
        pk.w = f2bf(v1.z) | (f2bf(v1.w) << 16);
        *(uint4*)((char*)lA + j * 4096 + t * 16) = pk;
      }
    } else {
      const ushortT* src = Ab + kt * 64;
#pragma unroll
      for (int j = 0; j < 4; ++j)
        gload_lds16(src + (size_t)j * 32 * K, (char*)lA + j * 4096 + t * 16);
    }
    __syncthreads();

    bf16x8 a0[4], a1[4], b0[4], b1[4];
#pragma unroll
    for (int m = 0; m < 4; ++m) {
      const int ro = (wm * 64 + m * 16 + lr) * 128;
      a0[m] = *(const bf16x8*)(lAc + ro + cc0);
      a1[m] = *(const bf16x8*)(lAc + ro + cc1);
    }
#pragma unroll
    for (int n = 0; n < 4; ++n) {
      const int ro = (wn * 64 + n * 16 + lr) * 128;
      b0[n] = *(const bf16x8*)(lBc + ro + cc0);
      b1[n] = *(const bf16x8*)(lBc + ro + cc1);
    }

    __builtin_amdgcn_s_setprio(1);
#pragma unroll
    for (int n = 0; n < 4; ++n)
#pragma unroll
      for (int m = 0; m < 4; ++m)
        acc[m][n] = __builtin_amdgcn_mfma_f32_16x16x32_bf16(a0[m], b0[n], acc[m][n], 0, 0, 0);
#pragma unroll
    for (int n = 0; n < 4; ++n)
#pragma unroll
      for (int m = 0; m < 4; ++m)
        acc[m][n] = __builtin_amdgcn_mfma_f32_16x16x32_bf16(a1[m], b1[n], acc[m][n], 0, 0, 0);
    __builtin_amdgcn_s_setprio(0);

    if (OUTP && bn == 0) {
      // wave w covers block rows w*32..w*32+31 (2 m-frags)
#pragma unroll
      for (int mi = 0; mi < 2; ++mi) {
        const int ro = (w * 32 + mi * 16 + lr) * 128;
        const bf16x8 xa0 = *(const bf16x8*)(lAc + ro + cc0);
        const bf16x8 xa1 = *(const bf16x8*)(lAc + ro + cc1);
        acc_out[mi] = __builtin_amdgcn_mfma_f32_16x16x32_bf16(xa0, wxf[kt][0], acc_out[mi], 0, 0, 0);
        acc_out[mi] = __builtin_amdgcn_mfma_f32_16x16x32_bf16(xa1, wxf[kt][1], acc_out[mi], 0, 0, 0);
      }
    }
    __syncthreads();
  }

  if (OUTP && bn == 0 && lr < 8) {
#pragma unroll
    for (int mi = 0; mi < 2; ++mi)
#pragma unroll
      for (int r = 0; r < 4; ++r)
        outp[(size_t)(bm * 128 + w * 32 + mi * 16 + q * 4 + r) * 8 + lr] = acc_out[mi][r];
  }

  const int row0 = bm * 128 + wm * 64 + q * 4;
  const int col0 = bn * 128 + wn * 64 + lr;
#pragma unroll
  for (int n = 0; n < 4; ++n) {
    const int col = col0 + n * 16;
    const float bvv = BIAS ? bias[col] : 0.f;
#pragma unroll
    for (int m = 0; m < 4; ++m) {
#pragma unroll
      for (int r = 0; r < 4; ++r) {
        float v = acc[m][n][r] + bvv;
        if (RELU) v = fmaxf(v, 0.f);
        C[(size_t)(row0 + m * 16 + r) * 512 + col] = (ushortT)f2bf(v);
      }
    }
  }
}

// ---------------- two-pass segment prefix-mean (unchanged) ----------------

__global__ __launch_bounds__(256)
void seg_sum_kernel(const ushortT* __restrict__ z, const int* __restrict__ gbnd,
                    float* __restrict__ part, int c0, int rows) {
  const int s  = (int)blockIdx.x >> 3;
  const int rg = (int)blockIdx.x & 7;
  const int t  = (int)threadIdx.x;

  const int gb0 = gbnd[s], gb1 = gbnd[s + 1];
  int beg = gb0 > c0 ? gb0 : c0;
  int end = gb1 < c0 + rows ? gb1 : c0 + rows;
  int len = end - beg; if (len < 0) len = 0;
  const int r0 = beg + ((len * rg) >> 3);
  const int r1 = beg + ((len * (rg + 1)) >> 3);

  float a0 = 0.f, a1 = 0.f;
  const uint32_t* __restrict__ zp = (const uint32_t*)z;
  int r = r0;
  for (; r + 8 <= r1; r += 8) {
    uint32_t v[8];
#pragma unroll
    for (int i = 0; i < 8; ++i) v[i] = zp[(size_t)(r + i - c0) * 256 + t];
#pragma unroll
    for (int i = 0; i < 8; ++i) { a0 += bf2f(v[i] & 0xffffu); a1 += bf2f(v[i] >> 16); }
  }
  for (; r < r1; ++r) {
    const uint32_t v = zp[(size_t)(r - c0) * 256 + t];
    a0 += bf2f(v & 0xffffu); a1 += bf2f(v >> 16);
  }
  float2 pv; pv.x = a0; pv.y = a1;
  ((float2*)part)[(s * 8 + rg) * 256 + t] = pv;
}

__global__ __launch_bounds__(256)
void seg_scan2_kernel(const ushortT* __restrict__ z, ushortT* __restrict__ gout,
                      const int* __restrict__ gbnd, const float* __restrict__ br,
                      const float* __restrict__ part,
                      const float* __restrict__ cin, float* __restrict__ cout,
                      int c0, int rows) {
  const int s  = (int)blockIdx.x >> 3;
  const int rg = (int)blockIdx.x & 7;
  const int t  = (int)threadIdx.x;

  const int gb0 = gbnd[s], gb1 = gbnd[s + 1];
  int beg = gb0 > c0 ? gb0 : c0;
  int end = gb1 < c0 + rows ? gb1 : c0 + rows;
  int len = end - beg; if (len < 0) len = 0;
  const int r0 = beg + ((len * rg) >> 3);
  const int r1 = beg + ((len * (rg + 1)) >> 3);

  const float2 cv = ((const float2*)cin)[s * 256 + t];
  float a0 = cv.x, a1 = cv.y;
  for (int q2 = 0; q2 < rg; ++q2) {
    const float2 pv = ((const float2*)part)[(s * 8 + q2) * 256 + t];
    a0 += pv.x; a1 += pv.y;
  }
  int cb = c0 - gb0; if (cb < 0) cb = 0;
  const int seglen = gb1 - gb0; if (cb > seglen) cb = seglen;
  const int cnt0 = cb + (r0 - beg);

  const float b0 = br[2 * t], b1v = br[2 * t + 1];
  const uint32_t* __restrict__ zp = (const uint32_t*)z;
  uint32_t* __restrict__ gp = (uint32_t*)gout;

  int r = r0;
  for (; r + 8 <= r1; r += 8) {
    uint32_t v[8];
#pragma unroll
    for (int i = 0; i < 8; ++i) v[i] = zp[(size_t)(r + i - c0) * 256 + t];
#pragma unroll
    for (int i = 0; i < 8; ++i) {
      a0 += bf2f(v[i] & 0xffffu);
      a1 += bf2f(v[i] >> 16);
      const float inv = 1.0f / (float)(cnt0 + (r + i) - r0 + 1);
      const float g0 = fmaxf(fmaf(a0, inv, b0), 0.f);
      const float g1 = fmaxf(fmaf(a1, inv, b1v), 0.f);
      gp[(size_t)(r + i - c0) * 256 + t] = f2bf(g0) | (f2bf(g1) << 16);
    }
  }
  for (; r < r1; ++r) {
    const uint32_t v = zp[(size_t)(r - c0) * 256 + t];
    a0 += bf2f(v & 0xffffu);
    a1 += bf2f(v >> 16);
    const float inv = 1.0f / (float)(cnt0 + r - r0 + 1);
    const float g0 = fmaxf(fmaf(a0, inv, b0), 0.f);
    const float g1 = fmaxf(fmaf(a1, inv, b1v), 0.f);
    gp[(size_t)(r - c0) * 256 + t] = f2bf(g0) | (f2bf(g1) << 16);
  }

  if (rg == 7) {
    float2 co; co.x = a0; co.y = a1;
    ((float2*)cout)[s * 256 + t] = co;
  }
}

// ---------------- final via MFMA: out[n,h] = partial(X@Wx) + g[n,:]@Wg ----------------

__global__ __launch_bounds__(256)
void final_mfma_kernel(const ushortT* __restrict__ g,
                       const ushortT* __restrict__ weffT, float* __restrict__ out) {
  __shared__ char lw[16 * 1296];
  const int t = (int)threadIdx.x;

#pragma unroll
  for (int i = 0; i < 5; ++i) {
    const int idx = i * 256 + t;
    const int row = idx / 80, c = idx % 80;
    *(uint4*)(lw + row * 1296 + c * 16) =
        *(const uint4*)((const char*)weffT + row * 1280 + c * 16);
  }
  __syncthreads();

  const int wv = t >> 6, lane = t & 63;
  const int q = lane >> 4, lr = lane & 15;
  const int rbase = (int)blockIdx.x * 128 + wv * 32;

  f32x4 acc[2];
  acc[0] = 0.f; acc[1] = 0.f;
  if (lr < 8) {
#pragma unroll
    for (int mt = 0; mt < 2; ++mt)
#pragma unroll
      for (int r = 0; r < 4; ++r)
        acc[mt][r] = out[(size_t)(rbase + mt * 16 + q * 4 + r) * 8 + lr];
  }

#pragma unroll
  for (int kk = 0; kk < 16; ++kk) {
    const bf16x8 b = *(const bf16x8*)(lw + lr * 1296 + (kk + 4) * 64 + q * 16);
#pragma unroll
    for (int mt = 0; mt < 2; ++mt) {
      const int row = rbase + mt * 16 + lr;
      const bf16x8 a = *(const bf16x8*)(g + (size_t)row * 512 + kk * 32 + q * 8);
      acc[mt] = __builtin_amdgcn_mfma_f32_16x16x32_bf16(a, b, acc[mt], 0, 0, 0);
    }
  }

  if (lr < 8) {
#pragma unroll
    for (int mt = 0; mt < 2; ++mt)
#pragma unroll
      for (int r = 0; r < 4; ++r)
        out[(size_t)(rbase + mt * 16 + q * 4 + r) * 8 + lr] = acc[mt][r];
  }
}

// ---------------- launch ----------------

extern "C" void kernel_launch(void* const* d_in, const int* in_sizes, int n_in,
                              void* d_out, int out_size, void* d_ws, size_t ws_size,
                              hipStream_t stream) {
  const float* X  = (const float*)d_in[0];
  const int*   sg = (const int*)d_in[1];
  const float* W1 = (const float*)d_in[2];
  const float* b1 = (const float*)d_in[3];
  const float* W2 = (const float*)d_in[4];
  const float* b2 = (const float*)d_in[5];
  const float* W3 = (const float*)d_in[6];
  const float* b3 = (const float*)d_in[7];
  const float* Wr = (const float*)d_in[8];
  const float* br = (const float*)d_in[9];
  const float* Wk = (const float*)d_in[10];
  const float* Wq = (const float*)d_in[11];
  float* out = (float*)d_out;

  const size_t szW1T  = 512 * 128 * 2;
  const size_t szWT   = 512 * 512 * 2;
  const size_t szWeff = 16 * 640 * 2;
  const size_t szPart = (size_t)NSEG * RSPL * 256 * 2 * 4;
  const size_t szCar  = (size_t)NSEG * 256 * 2 * 4;
  const size_t szBnd  = (NSEG + 1) * 4;
  const size_t fixed  = szW1T + 3 * szWT + szWeff + szPart + 2 * szCar + szBnd + 512;

  int CH = 0;
  const int cands[6] = {131072, 65536, 32768, 16384, 8192, 4096};
  for (int i = 0; i < 6; ++i) {
    const size_t need = fixed + 2 * (size_t)cands[i] * 512 * 2;
    if (need <= ws_size) { CH = cands[i]; break; }
  }
  if (CH == 0) CH = 4096;

  char* p = (char*)d_ws;
  ushortT* W1T   = (ushortT*)p; p += szW1T;
  ushortT* W2T   = (ushortT*)p; p += szWT;
  ushortT* W3T   = (ushortT*)p; p += szWT;
  ushortT* WrT   = (ushortT*)p; p += szWT;
  ushortT* weffT = (ushortT*)p; p += szWeff;
  float*   part  = (float*)p;   p += szPart;
  float*   carA  = (float*)p;   p += szCar;
  float*   carB  = (float*)p;   p += szCar;
  int*     gbnd  = (int*)p;     p += (szBnd + 255) & ~255ull;
  ushortT* p1    = (ushortT*)p; p += (size_t)CH * 512 * 2;
  ushortT* p2    = (ushortT*)p;

  transpose_bf16_kernel<<<(512 * 128 + 255) / 256, 256, 0, stream>>>(W1, W1T, 128, 512);
  transpose_bf16_kernel<<<(512 * 512 + 255) / 256, 256, 0, stream>>>(W2, W2T, 512, 512);
  transpose_bf16_kernel<<<(512 * 512 + 255) / 256, 256, 0, stream>>>(W3, W3T, 512, 512);
  transpose_bf16_kernel<<<(512 * 512 + 255) / 256, 256, 0, stream>>>(Wr, WrT, 512, 512);
  weff_kernel<<<640, 64, 0, stream>>>(Wk, Wq, weffT);
  seg_bounds_kernel<<<1, 512, 0, stream>>>(sg, gbnd);
  hipMemsetAsync(carA, 0, szCar, stream);

  int par = 0;
  for (int c0 = 0; c0 < N_TOK; c0 += CH) {
    const int gG = (CH / 128) * 4;
    float* cin  = par ? carB : carA;
    float* cout = par ? carA : carB;
    float* outc = out + (size_t)c0 * 8;
    gemm_m97_kernel<128, true,  true,  true,  true ><<<gG, 256, 0, stream>>>(
        X + (size_t)c0 * 128, W1T, b1, p1, weffT, outc);
    gemm_m97_kernel<512, true,  true,  false, false><<<gG, 256, 0, stream>>>(
        p1, W2T, b2, p2, nullptr, nullptr);
    gemm_m97_kernel<512, true,  true,  false, false><<<gG, 256, 0, stream>>>(
        p2, W3T, b3, p1, nullptr, nullptr);
    gemm_m97_kernel<512, false, false, false, false><<<gG, 256, 0, stream>>>(
        p1, WrT, nullptr, p2, nullptr, nullptr);
    seg_sum_kernel <<<NSEG * RSPL, 256, 0, stream>>>(p2, gbnd, part, c0, CH);
    seg_scan2_kernel<<<NSEG * RSPL, 256, 0, stream>>>(p2, p1, gbnd, br, part,
                                                      cin, cout, c0, CH);
    final_mfma_kernel<<<CH / 128, 256, 0, stream>>>(p1, weffT, outc);
    par ^= 1;
  }
}

// Round 15
// 424.526 us; speedup vs baseline: 1.5053x; 1.0447x over previous
//
#include <hip/hip_runtime.h>
#include <hip/hip_bf16.h>
#include <stdint.h>

typedef unsigned short ushortT;
typedef __bf16 bf16x8 __attribute__((ext_vector_type(8)));
typedef float f32x4 __attribute__((ext_vector_type(4)));

#define N_TOK 131072
#define NSEG  256
#define RSPL  8

__device__ __forceinline__ uint32_t f2bf(float f) {
  union { float f; uint32_t u; } c; c.f = f;
  uint32_t u = c.u;
  u += 0x7fffu + ((u >> 16) & 1u);   // RNE
  return u >> 16;
}
__device__ __forceinline__ float bf2f(uint32_t b) {
  union { uint32_t u; float f; } c; c.u = b << 16;
  return c.f;
}

__device__ __forceinline__ void gload_lds16(const void* g, void* l) {
  __builtin_amdgcn_global_load_lds(
      (const __attribute__((address_space(1))) void*)g,
      (__attribute__((address_space(3))) void*)l, 16, 0, 0);
}

// ---------------- prep kernels ----------------

// WT[n*Kd + k] = bf16(W[k*Nd + n]);  W is [Kd][Nd] row-major
__global__ void transpose_bf16_kernel(const float* __restrict__ W, ushortT* __restrict__ WT,
                                      int Kd, int Nd) {
  int i = blockIdx.x * 256 + threadIdx.x;
  if (i < Kd * Nd) {
    int n = i / Kd, k = i % Kd;
    WT[i] = (ushortT)f2bf(W[(size_t)k * Nd + n]);
  }
}

// weffT[h][c] = bf16( sum_d Wk[c,h*128+d]*Wq[h,d] / sqrt(128) ), h<8; rows 8..15 zero
__global__ void weff_kernel(const float* __restrict__ Wk, const float* __restrict__ Wq,
                            ushortT* __restrict__ weffT) {
  const int c = blockIdx.x;       // 640
  const int lane = threadIdx.x;   // 64
  const float rs = 0.08838834764831845f;
#pragma unroll
  for (int h = 0; h < 8; ++h) {
    float acc = Wk[(size_t)c * 1024 + h * 128 + lane] * Wq[h * 128 + lane]
              + Wk[(size_t)c * 1024 + h * 128 + 64 + lane] * Wq[h * 128 + 64 + lane];
#pragma unroll
    for (int off = 32; off >= 1; off >>= 1) acc += __shfl_xor(acc, off, 64);
    if (lane == 0) {
      weffT[h * 640 + c]       = (ushortT)f2bf(acc * rs);
      weffT[(h + 8) * 640 + c] = 0;
    }
  }
}

// gbnd[s] = first index with seg[i] >= s, s in [0, 256]
__global__ void seg_bounds_kernel(const int* __restrict__ seg, int* __restrict__ gbnd) {
  const int s = (int)threadIdx.x + (int)blockIdx.x * 512;
  if (s > NSEG) return;
  int lo = 0, hi = N_TOK;
  while (lo < hi) { int m = (lo + hi) >> 1; if (seg[m] < s) lo = m + 1; else hi = m; }
  gbnd[s] = lo;
}

// ---------------- m97-style GEMM: C[M,512] = relu?(A[M,K] @ W + bias) ----------------
// R12 config, verified best: (256,3) -> VGPR 76 + 64 AGPR, zero spill,
// conflicts=0, 780 TF @ K=512. R13/R14 lessons: (256,4) spills acc (192 MB
// WRITE, MfmaUtil 4%); any +24-reg fusion forces (256,2) and goes
// latency-bound. This kernel is pinned at exactly 3 blocks/CU.

template <int K, bool RELU, bool BIAS, bool XF32>
__global__ __launch_bounds__(256, 3)
void gemm_m97_kernel(const void* __restrict__ Av, const ushortT* __restrict__ BT,
                     const float* __restrict__ bias, ushortT* __restrict__ C) {
  __shared__ ushortT lA[128 * 64];
  __shared__ ushortT lB[128 * 64];
  constexpr int NT = K / 64;

  const int nwg  = (int)gridDim.x;
  const int cpx  = nwg >> 3;
  const int flat = (int)blockIdx.x;
  const int swz  = (flat & 7) * cpx + (flat >> 3);
  const int bm   = swz >> 2;
  const int bn   = swz & 3;

  const int t = (int)threadIdx.x;
  const int w = t >> 6, lane = t & 63;
  const int wm = w >> 1, wn = w & 1;
  const int q = lane >> 4, lr = lane & 15;

  const int srow = t >> 3;
  const int slc  = (t & 7) ^ (srow & 7);

  const ushortT* Ab = nullptr;
  const float*   Xf = nullptr;
  if (XF32) Xf = (const float*)Av + (size_t)(bm * 128 + srow) * 128 + slc * 8;
  else      Ab = (const ushortT*)Av + (size_t)(bm * 128 + srow) * K + slc * 8;
  const ushortT* Bg = BT + (size_t)(bn * 128 + srow) * K + slc * 8;

  f32x4 acc[4][4];
#pragma unroll
  for (int i = 0; i < 4; ++i)
#pragma unroll
    for (int j = 0; j < 4; ++j) acc[i][j] = 0.f;

  const int cc0 = (q ^ (lr & 7)) << 4;
  const int cc1 = ((4 + q) ^ (lr & 7)) << 4;
  const char* lAc = (const char*)lA;
  const char* lBc = (const char*)lB;

#pragma unroll 1
  for (int kt = 0; kt < NT; ++kt) {
    // B async staging first (overlaps the XF32 f32 register loads)
    {
      const ushortT* src = Bg + kt * 64;
#pragma unroll
      for (int j = 0; j < 4; ++j)
        gload_lds16(src + (size_t)j * 32 * K, (char*)lB + j * 4096 + t * 16);
    }
    if (XF32) {
      const float* src = Xf + kt * 64;
#pragma unroll
      for (int j = 0; j < 4; ++j) {
        const float4 v0 = *(const float4*)(src + (size_t)j * 32 * 128);
        const float4 v1 = *(const float4*)(src + (size_t)j * 32 * 128 + 4);
        uint4 pk;
        pk.x = f2bf(v0.x) | (f2bf(v0.y) << 16);
        pk.y = f2bf(v0.z) | (f2bf(v0.w) << 16);
        pk.z = f2bf(v1.x) | (f2bf(v1.y) << 16);
        pk.w = f2bf(v1.z) | (f2bf(v1.w) << 16);
        *(uint4*)((char*)lA + j * 4096 + t * 16) = pk;
      }
    } else {
      const ushortT* src = Ab + kt * 64;
#pragma unroll
      for (int j = 0; j < 4; ++j)
        gload_lds16(src + (size_t)j * 32 * K, (char*)lA + j * 4096 + t * 16);
    }
    __syncthreads();

    bf16x8 a0[4], a1[4], b0[4], b1[4];
#pragma unroll
    for (int m = 0; m < 4; ++m) {
      const int ro = (wm * 64 + m * 16 + lr) * 128;
      a0[m] = *(const bf16x8*)(lAc + ro + cc0);
      a1[m] = *(const bf16x8*)(lAc + ro + cc1);
    }
#pragma unroll
    for (int n = 0; n < 4; ++n) {
      const int ro = (wn * 64 + n * 16 + lr) * 128;
      b0[n] = *(const bf16x8*)(lBc + ro + cc0);
      b1[n] = *(const bf16x8*)(lBc + ro + cc1);
    }

    __builtin_amdgcn_s_setprio(1);
#pragma unroll
    for (int n = 0; n < 4; ++n)
#pragma unroll
      for (int m = 0; m < 4; ++m)
        acc[m][n] = __builtin_amdgcn_mfma_f32_16x16x32_bf16(a0[m], b0[n], acc[m][n], 0, 0, 0);
#pragma unroll
    for (int n = 0; n < 4; ++n)
#pragma unroll
      for (int m = 0; m < 4; ++m)
        acc[m][n] = __builtin_amdgcn_mfma_f32_16x16x32_bf16(a1[m], b1[n], acc[m][n], 0, 0, 0);
    __builtin_amdgcn_s_setprio(0);

    __syncthreads();
  }

  const int row0 = bm * 128 + wm * 64 + q * 4;
  const int col0 = bn * 128 + wn * 64 + lr;
#pragma unroll
  for (int n = 0; n < 4; ++n) {
    const int col = col0 + n * 16;
    const float bvv = BIAS ? bias[col] : 0.f;
#pragma unroll
    for (int m = 0; m < 4; ++m) {
#pragma unroll
      for (int r = 0; r < 4; ++r) {
        float v = acc[m][n][r] + bvv;
        if (RELU) v = fmaxf(v, 0.f);
        C[(size_t)(row0 + m * 16 + r) * 512 + col] = (ushortT)f2bf(v);
      }
    }
  }
}

// ---------------- two-pass segment prefix-mean ----------------

__global__ __launch_bounds__(256)
void seg_sum_kernel(const ushortT* __restrict__ z, const int* __restrict__ gbnd,
                    float* __restrict__ part, int c0, int rows) {
  const int s  = (int)blockIdx.x >> 3;
  const int rg = (int)blockIdx.x & 7;
  const int t  = (int)threadIdx.x;

  const int gb0 = gbnd[s], gb1 = gbnd[s + 1];
  int beg = gb0 > c0 ? gb0 : c0;
  int end = gb1 < c0 + rows ? gb1 : c0 + rows;
  int len = end - beg; if (len < 0) len = 0;
  const int r0 = beg + ((len * rg) >> 3);
  const int r1 = beg + ((len * (rg + 1)) >> 3);

  float a0 = 0.f, a1 = 0.f;
  const uint32_t* __restrict__ zp = (const uint32_t*)z;
  int r = r0;
  for (; r + 8 <= r1; r += 8) {
    uint32_t v[8];
#pragma unroll
    for (int i = 0; i < 8; ++i) v[i] = zp[(size_t)(r + i - c0) * 256 + t];
#pragma unroll
    for (int i = 0; i < 8; ++i) { a0 += bf2f(v[i] & 0xffffu); a1 += bf2f(v[i] >> 16); }
  }
  for (; r < r1; ++r) {
    const uint32_t v = zp[(size_t)(r - c0) * 256 + t];
    a0 += bf2f(v & 0xffffu); a1 += bf2f(v >> 16);
  }
  float2 pv; pv.x = a0; pv.y = a1;
  ((float2*)part)[(s * 8 + rg) * 256 + t] = pv;
}

__global__ __launch_bounds__(256)
void seg_scan2_kernel(const ushortT* __restrict__ z, ushortT* __restrict__ gout,
                      const int* __restrict__ gbnd, const float* __restrict__ br,
                      const float* __restrict__ part,
                      const float* __restrict__ cin, float* __restrict__ cout,
                      int c0, int rows) {
  const int s  = (int)blockIdx.x >> 3;
  const int rg = (int)blockIdx.x & 7;
  const int t  = (int)threadIdx.x;

  const int gb0 = gbnd[s], gb1 = gbnd[s + 1];
  int beg = gb0 > c0 ? gb0 : c0;
  int end = gb1 < c0 + rows ? gb1 : c0 + rows;
  int len = end - beg; if (len < 0) len = 0;
  const int r0 = beg + ((len * rg) >> 3);
  const int r1 = beg + ((len * (rg + 1)) >> 3);

  const float2 cv = ((const float2*)cin)[s * 256 + t];
  float a0 = cv.x, a1 = cv.y;
  for (int q2 = 0; q2 < rg; ++q2) {
    const float2 pv = ((const float2*)part)[(s * 8 + q2) * 256 + t];
    a0 += pv.x; a1 += pv.y;
  }
  int cb = c0 - gb0; if (cb < 0) cb = 0;
  const int seglen = gb1 - gb0; if (cb > seglen) cb = seglen;
  const int cnt0 = cb + (r0 - beg);

  const float b0 = br[2 * t], b1v = br[2 * t + 1];
  const uint32_t* __restrict__ zp = (const uint32_t*)z;
  uint32_t* __restrict__ gp = (uint32_t*)gout;

  int r = r0;
  for (; r + 8 <= r1; r += 8) {
    uint32_t v[8];
#pragma unroll
    for (int i = 0; i < 8; ++i) v[i] = zp[(size_t)(r + i - c0) * 256 + t];
#pragma unroll
    for (int i = 0; i < 8; ++i) {
      a0 += bf2f(v[i] & 0xffffu);
      a1 += bf2f(v[i] >> 16);
      // v_rcp_f32 (~1 ulp) instead of the ~10-inst IEEE divide expansion;
      // error ~1e-7 rel vs 3.3e-3 of absmax slack.
      const float inv = __builtin_amdgcn_rcpf((float)(cnt0 + (r + i) - r0 + 1));
      const float g0 = fmaxf(fmaf(a0, inv, b0), 0.f);
      const float g1 = fmaxf(fmaf(a1, inv, b1v), 0.f);
      gp[(size_t)(r + i - c0) * 256 + t] = f2bf(g0) | (f2bf(g1) << 16);
    }
  }
  for (; r < r1; ++r) {
    const uint32_t v = zp[(size_t)(r - c0) * 256 + t];
    a0 += bf2f(v & 0xffffu);
    a1 += bf2f(v >> 16);
    const float inv = __builtin_amdgcn_rcpf((float)(cnt0 + r - r0 + 1));
    const float g0 = fmaxf(fmaf(a0, inv, b0), 0.f);
    const float g1 = fmaxf(fmaf(a1, inv, b1v), 0.f);
    gp[(size_t)(r - c0) * 256 + t] = f2bf(g0) | (f2bf(g1) << 16);
  }

  if (rg == 7) {
    float2 co; co.x = a0; co.y = a1;
    ((float2*)cout)[s * 256 + t] = co;
  }
}

// ---------------- final via MFMA (R12 version): out = [X | g] @ weffT^T ----------------

__global__ __launch_bounds__(256)
void final_mfma_kernel(const float* __restrict__ X, const ushortT* __restrict__ g,
                       const ushortT* __restrict__ weffT, float* __restrict__ out) {
  __shared__ char lw[16 * 1296];
  const int t = (int)threadIdx.x;

#pragma unroll
  for (int i = 0; i < 5; ++i) {
    const int idx = i * 256 + t;
    const int row = idx / 80, c = idx % 80;
    *(uint4*)(lw + row * 1296 + c * 16) =
        *(const uint4*)((const char*)weffT + row * 1280 + c * 16);
  }
  __syncthreads();

  const int wv = t >> 6, lane = t & 63;
  const int q = lane >> 4, lr = lane & 15;
  const int rbase = (int)blockIdx.x * 128 + wv * 32;

  f32x4 acc[2];
  acc[0] = 0.f; acc[1] = 0.f;

#pragma unroll
  for (int kk = 0; kk < 20; ++kk) {
    const bf16x8 b = *(const bf16x8*)(lw + lr * 1296 + kk * 64 + q * 16);
#pragma unroll
    for (int mt = 0; mt < 2; ++mt) {
      const int row = rbase + mt * 16 + lr;
      union { ushortT u[8]; bf16x8 v; } a;
      if (kk < 4) {
        const float* xr = X + (size_t)row * 128 + kk * 32 + q * 8;
        const float4 v0 = *(const float4*)xr;
        const float4 v1 = *(const float4*)(xr + 4);
        a.u[0] = (ushortT)f2bf(v0.x); a.u[1] = (ushortT)f2bf(v0.y);
        a.u[2] = (ushortT)f2bf(v0.z); a.u[3] = (ushortT)f2bf(v0.w);
        a.u[4] = (ushortT)f2bf(v1.x); a.u[5] = (ushortT)f2bf(v1.y);
        a.u[6] = (ushortT)f2bf(v1.z); a.u[7] = (ushortT)f2bf(v1.w);
      } else {
        a.v = *(const bf16x8*)(g + (size_t)row * 512 + (kk - 4) * 32 + q * 8);
      }
      acc[mt] = __builtin_amdgcn_mfma_f32_16x16x32_bf16(a.v, b, acc[mt], 0, 0, 0);
    }
  }

  if (lr < 8) {
#pragma unroll
    for (int mt = 0; mt < 2; ++mt)
#pragma unroll
      for (int r = 0; r < 4; ++r)
        out[(size_t)(rbase + mt * 16 + q * 4 + r) * 8 + lr] = acc[mt][r];
  }
}

// ---------------- launch ----------------

extern "C" void kernel_launch(void* const* d_in, const int* in_sizes, int n_in,
                              void* d_out, int out_size, void* d_ws, size_t ws_size,
                              hipStream_t stream) {
  const float* X  = (const float*)d_in[0];
  const int*   sg = (const int*)d_in[1];
  const float* W1 = (const float*)d_in[2];
  const float* b1 = (const float*)d_in[3];
  const float* W2 = (const float*)d_in[4];
  const float* b2 = (const float*)d_in[5];
  const float* W3 = (const float*)d_in[6];
  const float* b3 = (const float*)d_in[7];
  const float* Wr = (const float*)d_in[8];
  const float* br = (const float*)d_in[9];
  const float* Wk = (const float*)d_in[10];
  const float* Wq = (const float*)d_in[11];
  float* out = (float*)d_out;

  const size_t szW1T  = 512 * 128 * 2;
  const size_t szWT   = 512 * 512 * 2;
  const size_t szWeff = 16 * 640 * 2;
  const size_t szPart = (size_t)NSEG * RSPL * 256 * 2 * 4;
  const size_t szCar  = (size_t)NSEG * 256 * 2 * 4;
  const size_t szBnd  = (NSEG + 1) * 4;
  const size_t fixed  = szW1T + 3 * szWT + szWeff + szPart + 2 * szCar + szBnd + 512;

  int CH = 0;
  const int cands[6] = {131072, 65536, 32768, 16384, 8192, 4096};
  for (int i = 0; i < 6; ++i) {
    const size_t need = fixed + 2 * (size_t)cands[i] * 512 * 2;
    if (need <= ws_size) { CH = cands[i]; break; }
  }
  if (CH == 0) CH = 4096;

  char* p = (char*)d_ws;
  ushortT* W1T   = (ushortT*)p; p += szW1T;
  ushortT* W2T   = (ushortT*)p; p += szWT;
  ushortT* W3T   = (ushortT*)p; p += szWT;
  ushortT* WrT   = (ushortT*)p; p += szWT;
  ushortT* weffT = (ushortT*)p; p += szWeff;
  float*   part  = (float*)p;   p += szPart;
  float*   carA  = (float*)p;   p += szCar;
  float*   carB  = (float*)p;   p += szCar;
  int*     gbnd  = (int*)p;     p += (szBnd + 255) & ~255ull;
  ushortT* p1    = (ushortT*)p; p += (size_t)CH * 512 * 2;
  ushortT* p2    = (ushortT*)p;

  transpose_bf16_kernel<<<(512 * 128 + 255) / 256, 256, 0, stream>>>(W1, W1T, 128, 512);
  transpose_bf16_kernel<<<(512 * 512 + 255) / 256, 256, 0, stream>>>(W2, W2T, 512, 512);
  transpose_bf16_kernel<<<(512 * 512 + 255) / 256, 256, 0, stream>>>(W3, W3T, 512, 512);
  transpose_bf16_kernel<<<(512 * 512 + 255) / 256, 256, 0, stream>>>(Wr, WrT, 512, 512);
  weff_kernel<<<640, 64, 0, stream>>>(Wk, Wq, weffT);
  seg_bounds_kernel<<<1, 512, 0, stream>>>(sg, gbnd);
  hipMemsetAsync(carA, 0, szCar, stream);

  int par = 0;
  for (int c0 = 0; c0 < N_TOK; c0 += CH) {
    const int gG = (CH / 128) * 4;
    float* cin  = par ? carB : carA;
    float* cout = par ? carA : carB;
    gemm_m97_kernel<128, true,  true,  true ><<<gG, 256, 0, stream>>>(X + (size_t)c0 * 128, W1T, b1, p1);
    gemm_m97_kernel<512, true,  true,  false><<<gG, 256, 0, stream>>>(p1, W2T, b2, p2);
    gemm_m97_kernel<512, true,  true,  false><<<gG, 256, 0, stream>>>(p2, W3T, b3, p1);
    gemm_m97_kernel<512, false, false, false><<<gG, 256, 0, stream>>>(p1, WrT, nullptr, p2);
    seg_sum_kernel <<<NSEG * RSPL, 256, 0, stream>>>(p2, gbnd, part, c0, CH);
    seg_scan2_kernel<<<NSEG * RSPL, 256, 0, stream>>>(p2, p1, gbnd, br, part,
                                                      cin, cout, c0, CH);
    final_mfma_kernel<<<CH / 128, 256, 0, stream>>>(X + (size_t)c0 * 128, p1, weffT,
                                                    out + (size_t)c0 * 8);
    par ^= 1;
  }
}